// Round 13
// baseline (47.518 us; speedup 1.0000x reference)
//
#include <hip/hip_runtime.h>

// AdditiveAttention: B=2,H=8,Q=512,K=512,D=64
//   scores[b,h,q,k] = V_b + sum_d V_w[d]*tanh(q_proj[q,d] + k_proj[k,d])
//
// tanh(x) = 1 - 2/(1+e^{2x});  e^{2(qp+kp)} = eq*gk,
//   eq = exp2(C*qp), gk = exp2(C*kp), C = 2*log2(e)
// term_d = Vw[d]/A_d,  A_d = 1 + eq_d*gk_d;  score = (Vb+sumVw) - 2*sum term_d
// tree8: 1 v_rcp per 8 elements (R7-proven), ~3.9 VALU/elem.
//
// R12 lesson: VALUBusy*dur ~= op-count model (instructions are fine); the
// ~60% issue-idle came from LDS-capped occupancy (24.6KB -> 6 blk/CU vs the
// 8 the grid wants). R13: NO k-side LDS tile -- G (32B/group/lane) read
// straight from L2 per group; LDS = 8KB q-tile only -> 8 blk/CU, 32 w/CU.

#define BHX 16
#define SEQ 512
#define DDIM 64
#define QT 32
#define KT 64

typedef float f4 __attribute__((ext_vector_type(4)));

// Both projections in one launch. blocks 0..255: query->eq, 256..511: keys->gk.
// 32 rows/block, 8 rows/wave. lane = output dim d; W row in VGPRs (NO pins);
// X rows via wave-uniform s_loads.
__global__ __launch_bounds__(256) void proj_kernel(
    const float* __restrict__ query, const float* __restrict__ keys,
    const float* __restrict__ Wa_w,  const float* __restrict__ Wa_b,
    const float* __restrict__ Ua_w,  const float* __restrict__ Ua_b,
    float* __restrict__ eq, float* __restrict__ gk)
{
  const int t = threadIdx.x, lane = t & 63, wave = t >> 6;
  const bool is_k = blockIdx.x >= 256;
  const float* __restrict__ X  = is_k ? keys : query;
  const float* __restrict__ W  = is_k ? Ua_w : Wa_w;
  const float* __restrict__ Bv = is_k ? Ua_b : Wa_b;
  float* __restrict__ out      = is_k ? gk : eq;
  const int row0 = (blockIdx.x & 255) * 32;

  float w[64];
  const float4* W4 = (const float4*)(W + lane * DDIM);
#pragma unroll
  for (int i = 0; i < 16; ++i) {
    float4 v = W4[i];
    w[4*i] = v.x; w[4*i+1] = v.y; w[4*i+2] = v.z; w[4*i+3] = v.w;
  }

  const float C = 2.885390081777926815f;          // 2*log2(e)
  const float b = Bv[lane];

#pragma unroll 1
  for (int i = 0; i < 8; ++i) {
    const int r   = row0 + wave * 8 + i;
    const int off = __builtin_amdgcn_readfirstlane(r * DDIM);
    const float* xr = X + off;                    // wave-uniform -> s_load
    float a0 = 0, a1 = 0, a2 = 0, a3 = 0;
#pragma unroll
    for (int e = 0; e < 64; e += 4) {
      a0 = __builtin_fmaf(xr[e],     w[e],     a0);
      a1 = __builtin_fmaf(xr[e + 1], w[e + 1], a1);
      a2 = __builtin_fmaf(xr[e + 2], w[e + 2], a2);
      a3 = __builtin_fmaf(xr[e + 3], w[e + 3], a3);
    }
    float p = ((a0 + a1) + (a2 + a3)) + b;
    out[(size_t)r * DDIM + lane] = __builtin_amdgcn_exp2f(C * p);
  }
}

// Grid (8,16,16)=2048 blocks = exactly 8 blocks/CU, one full resident round.
// Block = 64 k (lanes) x 32 q (8 per wave). LDS: 8KB q-tile ONLY.
// Per d-group of 8: lane reads its 32B G-slice from global (L2-resident),
// e-values broadcast from LDS, tree8 -> 1 rcp.
__global__ __launch_bounds__(256, 8) void score_kernel(
    const float* __restrict__ eq,   // [BH*512][64]
    const float* __restrict__ gk,   // [BH*512][64]
    const float* __restrict__ Vw,   // [64]
    const float* __restrict__ Vb,   // [1]
    float* __restrict__ out)        // [BH,512,512]
{
  __shared__ float ql[QT * DDIM];   // 8 KB

  const int bh   = blockIdx.z;
  const int q0   = blockIdx.y * QT;
  const int k0   = blockIdx.x * KT;
  const int t    = threadIdx.x;
  const int lane = t & 63;
  const int wave = t >> 6;

  // ---- stage q-tile (coalesced, 2 float4 per thread) ----
  {
    const float4* src = (const float4*)(eq + (size_t)(bh * SEQ + q0) * DDIM);
    float4* dst = (float4*)ql;
    dst[t]       = src[t];
    dst[t + 256] = src[t + 256];
  }

  // acc0 = V_b + sum_d V_w[d]  (uniform)
  float acc0 = Vb[0];
#pragma unroll
  for (int d = 0; d < 64; ++d) acc0 += Vw[d];

  __syncthreads();

  float acc[8] = {0.f, 0.f, 0.f, 0.f, 0.f, 0.f, 0.f, 0.f};
  const int qrow0 = wave * 8;
  const float* gbase = gk + (size_t)(bh * SEQ + k0 + lane) * DDIM;

#pragma unroll 1
  for (int g = 0; g < 8; ++g) {           // d-groups of 8
    // lane's 8 k-side values: one 32B contiguous global read (L2-hit)
    const f4 G0 = *(const f4*)(gbase + 8 * g);
    const f4 G1 = *(const f4*)(gbase + 8 * g + 4);
    // uniform Vw slice (s_loads)
    float vw[8];
#pragma unroll
    for (int j = 0; j < 8; ++j) vw[j] = Vw[8 * g + j];

#pragma unroll
    for (int qi = 0; qi < 8; ++qi) {      // fully unrolled: acc[] static
      const f4* ev = (const f4*)(ql + (qrow0 + qi) * DDIM + 8 * g);
      const f4 e0 = ev[0];                // broadcast ds_read_b128
      const f4 e1 = ev[1];
      float A[8];
      A[0] = __builtin_fmaf(e0.x, G0.x, 1.0f);
      A[1] = __builtin_fmaf(e0.y, G0.y, 1.0f);
      A[2] = __builtin_fmaf(e0.z, G0.z, 1.0f);
      A[3] = __builtin_fmaf(e0.w, G0.w, 1.0f);
      A[4] = __builtin_fmaf(e1.x, G1.x, 1.0f);
      A[5] = __builtin_fmaf(e1.y, G1.y, 1.0f);
      A[6] = __builtin_fmaf(e1.z, G1.z, 1.0f);
      A[7] = __builtin_fmaf(e1.w, G1.w, 1.0f);
      // tree8: sum_j vw[j]/A[j] = num/P, 1 rcp
      const float n01 = __builtin_fmaf(vw[1], A[0], vw[0] * A[1]);
      const float n23 = __builtin_fmaf(vw[3], A[2], vw[2] * A[3]);
      const float n45 = __builtin_fmaf(vw[5], A[4], vw[4] * A[5]);
      const float n67 = __builtin_fmaf(vw[7], A[6], vw[6] * A[7]);
      const float P01 = A[0] * A[1], P23 = A[2] * A[3];
      const float P45 = A[4] * A[5], P67 = A[6] * A[7];
      const float n0123 = __builtin_fmaf(n23, P01, n01 * P23);
      const float n4567 = __builtin_fmaf(n67, P45, n45 * P67);
      const float P0123 = P01 * P23, P4567 = P45 * P67;
      const float num = __builtin_fmaf(n4567, P0123, n0123 * P4567);
      const float P   = P0123 * P4567;    // product of 8 A's >= 1: safe
      acc[qi] = __builtin_fmaf(num, __builtin_amdgcn_rcpf(P), acc[qi]);
    }
  }

  const size_t obase = (size_t)(bh * SEQ + q0 + qrow0) * SEQ + k0 + lane;
#pragma unroll
  for (int qi = 0; qi < 8; ++qi)
    out[obase + (size_t)qi * SEQ] = __builtin_fmaf(-2.f, acc[qi], acc0);
}

extern "C" void kernel_launch(void* const* d_in, const int* in_sizes, int n_in,
                              void* d_out, int out_size, void* d_ws, size_t ws_size,
                              hipStream_t stream) {
  const float* query = (const float*)d_in[0];  // [2,8,512,64]
  const float* keys  = (const float*)d_in[1];  // [2,8,512,64]
  const float* Wa_w  = (const float*)d_in[2];  // [64,64]
  const float* Wa_b  = (const float*)d_in[3];  // [64]
  const float* Ua_w  = (const float*)d_in[4];  // [64,64]
  const float* Ua_b  = (const float*)d_in[5];  // [64]
  const float* V_w   = (const float*)d_in[6];  // [64]
  const float* V_b   = (const float*)d_in[7];  // [1]
  float* out = (float*)d_out;

  const int R = BHX * SEQ;                 // 8192 rows each side
  float* eq = (float*)d_ws;                // 2 MiB
  float* gk = eq + (size_t)R * DDIM;       // 2 MiB

  proj_kernel<<<512, 256, 0, stream>>>(query, keys, Wa_w, Wa_b,
                                       Ua_w, Ua_b, eq, gk);

  dim3 grid(SEQ / KT, SEQ / QT, BHX);      // (8,16,16) = 2048 blocks
  score_kernel<<<grid, 256, 0, stream>>>(eq, gk, V_w, V_b, out);
}